// Round 5
// baseline (522.652 us; speedup 1.0000x reference)
//
#include <hip/hip_runtime.h>

#define N_EDGES 160000
#define C_EMB 32
#define N_RBF 32

typedef float floatx4 __attribute__((ext_vector_type(4)));

#define PI_F 3.14159265358979323f

// ============================ K1: compact features ============================
// Per edge -> ws_c[96] (env & hz folded in), ws_basis[28] (27 basis floats).
#define EPB1 32
#define T1 256

__global__ __launch_bounds__(T1) void k1_features(
    const int* __restrict__ atomic_numbers,
    const int* __restrict__ nbr,
    const float* __restrict__ ev,
    const float* __restrict__ z_table,
    const float* __restrict__ z_map_W,
    const float* __restrict__ dense_W,
    const float* __restrict__ dense_b,
    const float* __restrict__ rbf_beta,
    const float* __restrict__ rbf_centres,
    float* __restrict__ ws_c,       // (N_EDGES, 96)
    float* __restrict__ ws_basis)   // (N_EDGES, 28)
{
    __shared__ float s_hi[EPB1][C_EMB];
    __shared__ float s_hj[EPB1][C_EMB];
    __shared__ float s_rbf[EPB1][N_RBF];
    __shared__ float s_hz[EPB1][C_EMB];
    __shared__ float s_env[EPB1];

    const int tid = threadIdx.x;
    const int e0 = blockIdx.x * EPB1;

    // gather atom embeddings
    for (int idx = tid; idx < EPB1 * C_EMB; idx += T1) {
        int e = idx >> 5, k = idx & 31, ge = e0 + e;
        s_hi[e][k] = z_table[atomic_numbers[nbr[ge]] * C_EMB + k];
        s_hj[e][k] = z_table[atomic_numbers[nbr[N_EDGES + ge]] * C_EMB + k];
    }
    // rbf + env
    for (int idx = tid; idx < EPB1 * N_RBF; idx += T1) {
        int e = idx >> 5, n = idx & 31, ge = e0 + e;
        float x = ev[ge * 3 + 0], y = ev[ge * 3 + 1], z = ev[ge * 3 + 2];
        float r = sqrtf(x * x + y * y + z * z);
        float d = __expf(-r) - rbf_centres[n];
        s_rbf[e][n] = __expf(-rbf_beta[n] * d * d);
        if (n == 0) {
            s_env[e] = (r < 5.0f) ? 0.5f * (__cosf(PI_F * r * 0.2f) + 1.0f) : 0.0f;
        }
    }
    // geometric basis -> ws
    for (int idx = tid; idx < EPB1 * 27; idx += T1) {
        int e = idx / 27, t = idx - e * 27, ge = e0 + e;
        float x = ev[ge * 3 + 0], y = ev[ge * 3 + 1], z = ev[ge * 3 + 2];
        float rinv = rsqrtf(x * x + y * y + z * z);
        float vx = x * rinv, vy = y * rinv, vz = z * rinv;
        float val;
        if (t < 9) {
            val = (t == 0 || t == 4 || t == 8) ? 1.0f : 0.0f;
        } else if (t < 18) {
            int p = t - 9;
            switch (p) {
                case 1: val = -vz; break;
                case 2: val =  vy; break;
                case 3: val =  vz; break;
                case 5: val = -vx; break;
                case 6: val = -vy; break;
                case 7: val =  vx; break;
                default: val = 0.0f; break;
            }
        } else {
            int p = t - 18;
            int i = p / 3, j = p - 3 * i;
            float ri = (i == 0) ? vx : ((i == 1) ? vy : vz);
            float rj = (j == 0) ? vx : ((j == 1) ? vy : vz);
            val = ri * rj - ((i == j) ? (1.0f / 3.0f) : 0.0f);
        }
        ws_basis[ge * 28 + t] = val;
    }
    __syncthreads();

    // h_z
    for (int idx = tid; idx < EPB1 * C_EMB; idx += T1) {
        int e = idx >> 5, cc = idx & 31;
        const float4* Wi  = (const float4*)(z_map_W + cc * 64);
        const float4* hi4 = (const float4*)s_hi[e];
        const float4* hj4 = (const float4*)s_hj[e];
        float acc = 0.0f;
        #pragma unroll
        for (int k = 0; k < 8; ++k) {
            float4 w = Wi[k]; float4 h = hi4[k];
            acc += w.x * h.x + w.y * h.y + w.z * h.z + w.w * h.w;
        }
        #pragma unroll
        for (int k = 0; k < 8; ++k) {
            float4 w = Wi[8 + k]; float4 h = hj4[k];
            acc += w.x * h.x + w.y * h.y + w.z * h.z + w.w * h.w;
        }
        s_hz[e][cc] = acc;
    }
    __syncthreads();

    // c = (b + rbf.W) * env * hz  -> ws (coalesced rows of 96)
    for (int idx = tid; idx < EPB1 * 96; idx += T1) {
        int e = idx / 96, m = idx - e * 96, ge = e0 + e;
        int cc = m & 31;
        const float4* Wd  = (const float4*)(dense_W + m * 32);
        const float4* rb4 = (const float4*)s_rbf[e];
        float acc = dense_b[m];
        #pragma unroll
        for (int n = 0; n < 8; ++n) {
            float4 w = Wd[n]; float4 rv = rb4[n];
            acc += w.x * rv.x + w.y * rv.y + w.z * rv.z + w.w * rv.w;
        }
        ws_c[(size_t)ge * 96 + m] = acc * s_env[e] * s_hz[e][cc];
    }
}

// ==================== K2: persistent streaming expansion ======================
// Grid-stride, no LDS, no barriers. One wave = one (region, edge) per iter:
// 288 floats = 72 float4s; lane handles fl4 `lane`, lanes 0..7 also fl4 64+lane.
// Per-lane (cc,p) index sets are loop-invariant. Loads hit L3-resident ws.
#define T2 256
#define NBLK2 2048

__global__ __launch_bounds__(T2) void k2_expand(
    const float* __restrict__ ws_c,     // (N_EDGES, 96)
    const float* __restrict__ ws_basis, // (N_EDGES, 28)
    float* __restrict__ out)
{
    const int lane = threadIdx.x & 63;
    const int gw   = (blockIdx.x * T2 + threadIdx.x) >> 6;   // global wave id
    const int NW   = (NBLK2 * T2) >> 6;                      // total waves

    // lane-constant index decompositions
    int cA[4], pA[4], cB[4], pB[4];
    #pragma unroll
    for (int u = 0; u < 4; ++u) {
        int f = 4 * lane + u;
        cA[u] = f / 9; pA[u] = f - 9 * cA[u];
    }
    const bool tail = lane < 8;
    #pragma unroll
    for (int u = 0; u < 4; ++u) {
        int f = 256 + 4 * lane + u;
        cB[u] = f / 9; pB[u] = f - 9 * cB[u];
    }

    for (int r = 0; r < 3; ++r) {
        const float* cr = ws_c + 32 * r;
        const float* br = ws_basis + 9 * r;
        float* outr = out + (size_t)r * N_EDGES * 288;
        #pragma unroll 2
        for (int e = gw; e < N_EDGES; e += NW) {
            const float* cb = cr + (size_t)e * 96;
            const float* bb = br + (size_t)e * 28;
            float* ob = outr + (size_t)e * 288;
            floatx4 v;
            #pragma unroll
            for (int u = 0; u < 4; ++u) v[u] = cb[cA[u]] * bb[pA[u]];
            *(floatx4*)(ob + 4 * lane) = v;
            if (tail) {
                floatx4 w;
                #pragma unroll
                for (int u = 0; u < 4; ++u) w[u] = cb[cB[u]] * bb[pB[u]];
                *(floatx4*)(ob + 256 + 4 * lane) = w;
            }
        }
    }
}

// ===================== Fallback: proven R1 single kernel ======================
#define EPBF 16
#define TF 256

__global__ __launch_bounds__(TF) void edge_embed_fallback(
    const int* __restrict__ atomic_numbers,
    const int* __restrict__ nbr,
    const float* __restrict__ ev,
    const float* __restrict__ z_table,
    const float* __restrict__ z_map_W,
    const float* __restrict__ dense_W,
    const float* __restrict__ dense_b,
    const float* __restrict__ rbf_beta,
    const float* __restrict__ rbf_centres,
    float* __restrict__ out)
{
    __shared__ float s_hi[EPBF][C_EMB];
    __shared__ float s_hj[EPBF][C_EMB];
    __shared__ float s_rbf[EPBF][N_RBF];
    __shared__ float s_hz[EPBF][C_EMB];
    __shared__ float s_c[EPBF][96];
    __shared__ float s_basis[EPBF][28];

    const int tid = threadIdx.x;
    const int e0 = blockIdx.x * EPBF;

    for (int idx = tid; idx < EPBF * C_EMB; idx += TF) {
        int e = idx >> 5, k = idx & 31, ge = e0 + e;
        s_hi[e][k] = z_table[atomic_numbers[nbr[ge]] * C_EMB + k];
        s_hj[e][k] = z_table[atomic_numbers[nbr[N_EDGES + ge]] * C_EMB + k];
    }
    for (int idx = tid; idx < EPBF * N_RBF; idx += TF) {
        int e = idx >> 5, n = idx & 31, ge = e0 + e;
        float x = ev[ge * 3 + 0], y = ev[ge * 3 + 1], z = ev[ge * 3 + 2];
        float r = sqrtf(x * x + y * y + z * z);
        float d = __expf(-r) - rbf_centres[n];
        s_rbf[e][n] = __expf(-rbf_beta[n] * d * d);
        if (n == 0)
            s_basis[e][27] = (r < 5.0f) ? 0.5f * (__cosf(PI_F * r * 0.2f) + 1.0f) : 0.0f;
    }
    for (int idx = tid; idx < EPBF * 27; idx += TF) {
        int e = idx / 27, t = idx - e * 27, ge = e0 + e;
        float x = ev[ge * 3 + 0], y = ev[ge * 3 + 1], z = ev[ge * 3 + 2];
        float rinv = rsqrtf(x * x + y * y + z * z);
        float vx = x * rinv, vy = y * rinv, vz = z * rinv;
        float val;
        if (t < 9) val = (t == 0 || t == 4 || t == 8) ? 1.0f : 0.0f;
        else if (t < 18) {
            int p = t - 9;
            switch (p) {
                case 1: val = -vz; break;
                case 2: val =  vy; break;
                case 3: val =  vz; break;
                case 5: val = -vx; break;
                case 6: val = -vy; break;
                case 7: val =  vx; break;
                default: val = 0.0f; break;
            }
        } else {
            int p = t - 18;
            int i = p / 3, j = p - 3 * i;
            float ri = (i == 0) ? vx : ((i == 1) ? vy : vz);
            float rj = (j == 0) ? vx : ((j == 1) ? vy : vz);
            val = ri * rj - ((i == j) ? (1.0f / 3.0f) : 0.0f);
        }
        s_basis[e][t] = val;
    }
    __syncthreads();
    for (int idx = tid; idx < EPBF * C_EMB; idx += TF) {
        int e = idx >> 5, cc = idx & 31;
        const float4* Wi  = (const float4*)(z_map_W + cc * 64);
        const float4* hi4 = (const float4*)s_hi[e];
        const float4* hj4 = (const float4*)s_hj[e];
        float acc = 0.0f;
        #pragma unroll
        for (int k = 0; k < 8; ++k) {
            float4 w = Wi[k]; float4 h = hi4[k];
            acc += w.x * h.x + w.y * h.y + w.z * h.z + w.w * h.w;
        }
        #pragma unroll
        for (int k = 0; k < 8; ++k) {
            float4 w = Wi[8 + k]; float4 h = hj4[k];
            acc += w.x * h.x + w.y * h.y + w.z * h.z + w.w * h.w;
        }
        s_hz[e][cc] = acc;
    }
    __syncthreads();
    for (int idx = tid; idx < EPBF * 96; idx += TF) {
        int e = idx / 96, m = idx - e * 96;
        int cc = m & 31;
        const float4* Wd  = (const float4*)(dense_W + m * 32);
        const float4* rb4 = (const float4*)s_rbf[e];
        float acc = dense_b[m];
        #pragma unroll
        for (int n = 0; n < 8; ++n) {
            float4 w = Wd[n]; float4 rv = rb4[n];
            acc += w.x * rv.x + w.y * rv.y + w.z * rv.z + w.w * rv.w;
        }
        s_c[e][m] = acc * s_basis[e][27] * s_hz[e][cc];
    }
    __syncthreads();
    float* outI = out + (size_t)e0 * 288;
    float* outA = out + (size_t)N_EDGES * 288 + (size_t)e0 * 288;
    float* outS = out + (size_t)N_EDGES * 576 + (size_t)e0 * 288;
    const int NQ = EPBF * 288 / 4;
    for (int q = tid; q < NQ; q += TF) {
        int fbase = q * 4;
        floatx4 aI, aA, aS;
        #pragma unroll
        for (int u = 0; u < 4; ++u) {
            int f = fbase + u;
            int e = f / 288;
            int rem = f - e * 288;
            int cc = rem / 9;
            int p = rem - cc * 9;
            aI[u] = s_c[e][cc]      * s_basis[e][p];
            aA[u] = s_c[e][32 + cc] * s_basis[e][9 + p];
            aS[u] = s_c[e][64 + cc] * s_basis[e][18 + p];
        }
        ((floatx4*)outI)[q] = aI;
        ((floatx4*)outA)[q] = aA;
        ((floatx4*)outS)[q] = aS;
    }
}

extern "C" void kernel_launch(void* const* d_in, const int* in_sizes, int n_in,
                              void* d_out, int out_size, void* d_ws, size_t ws_size,
                              hipStream_t stream) {
    const int*   an  = (const int*)d_in[0];
    const int*   nbr = (const int*)d_in[1];
    const float* ev  = (const float*)d_in[2];
    const float* zt  = (const float*)d_in[3];
    const float* zw  = (const float*)d_in[4];
    const float* dw  = (const float*)d_in[5];
    const float* db  = (const float*)d_in[6];
    const float* rb  = (const float*)d_in[7];
    const float* rc  = (const float*)d_in[8];
    float* outp = (float*)d_out;

    const size_t need_c = (size_t)N_EDGES * 96 * sizeof(float);   // 61.44 MB
    const size_t need_b = (size_t)N_EDGES * 28 * sizeof(float);   // 17.92 MB

    if (ws_size >= need_c + need_b) {
        float* ws_c     = (float*)d_ws;
        float* ws_basis = (float*)((char*)d_ws + need_c);
        k1_features<<<dim3(N_EDGES / EPB1), T1, 0, stream>>>(
            an, nbr, ev, zt, zw, dw, db, rb, rc, ws_c, ws_basis);
        k2_expand<<<dim3(NBLK2), T2, 0, stream>>>(ws_c, ws_basis, outp);
    } else {
        edge_embed_fallback<<<dim3(N_EDGES / EPBF), TF, 0, stream>>>(
            an, nbr, ev, zt, zw, dw, db, rb, rc, outp);
    }
}

// Round 6
// 378.020 us; speedup vs baseline: 1.3826x; 1.3826x over previous
//
#include <hip/hip_runtime.h>

#define N_EDGES 160000
#define C_EMB 32
#define N_RBF 32
#define Z_MAX 119

typedef float floatx4 __attribute__((ext_vector_type(4)));

#define PI_F 3.14159265358979323f
#define RSZ ((size_t)N_EDGES * 288)

// =========================== K0: F/G pair tables ==============================
// F[z][cc] = sum_k zt[z][k]*W[cc][k];  G[z][cc] = sum_k zt[z][k]*W[cc][32+k]
__global__ __launch_bounds__(256) void k0_tables(
    const float* __restrict__ zt,   // (119, 32)
    const float* __restrict__ zw,   // (32, 64) row-major
    float* __restrict__ FG)         // F=[0,3808), G=[3808,7616)
{
    int i = blockIdx.x * 256 + threadIdx.x;
    if (i >= 2 * Z_MAX * C_EMB) return;
    int which = i / (Z_MAX * C_EMB);
    int j = i - which * Z_MAX * C_EMB;
    int z = j >> 5, cc = j & 31;
    const float* wrow = zw + cc * 64 + which * 32;
    const float* zrow = zt + z * 32;
    float acc = 0.0f;
    #pragma unroll
    for (int k = 0; k < 32; ++k) acc += zrow[k] * wrow[k];
    FG[i] = acc;
}

// ===================== kA: per-edge compact record (128 fl) ===================
// rec[e][0..95] = c (env & h_z folded), rec[e][96..122] = basis27
#define EPA 64
#define TA 256

__global__ __launch_bounds__(TA) void kA_features(
    const int* __restrict__ atomic_numbers,
    const int* __restrict__ nbr,
    const float* __restrict__ ev,
    const float* __restrict__ dense_W,     // (96, 32)
    const float* __restrict__ dense_b,     // (96,)
    const float* __restrict__ rbf_beta,
    const float* __restrict__ rbf_centres,
    const float* __restrict__ FG,
    float* __restrict__ rec)               // (N_EDGES, 128)
{
    __shared__ int   s_zi[EPA];
    __shared__ int   s_zj[EPA];
    __shared__ float s_rbf[EPA][N_RBF];
    __shared__ float s_env[EPA];

    const int tid = threadIdx.x;
    const int e0 = blockIdx.x * EPA;

    if (tid < EPA)            s_zi[tid]       = atomic_numbers[nbr[e0 + tid]];
    else if (tid < 2 * EPA)   s_zj[tid - EPA] = atomic_numbers[nbr[N_EDGES + e0 + tid - EPA]];

    // rbf + env
    for (int idx = tid; idx < EPA * N_RBF; idx += TA) {
        int e = idx >> 5, n = idx & 31, ge = e0 + e;
        float x = ev[ge * 3 + 0], y = ev[ge * 3 + 1], z = ev[ge * 3 + 2];
        float r = sqrtf(x * x + y * y + z * z);
        float d = __expf(-r) - rbf_centres[n];
        s_rbf[e][n] = __expf(-rbf_beta[n] * d * d);
        if (n == 0)
            s_env[e] = (r < 5.0f) ? 0.5f * (__cosf(PI_F * r * 0.2f) + 1.0f) : 0.0f;
    }

    // basis -> rec directly (no LDS)
    for (int idx = tid; idx < EPA * 27; idx += TA) {
        int e = idx / 27, t = idx - e * 27, ge = e0 + e;
        float x = ev[ge * 3 + 0], y = ev[ge * 3 + 1], z = ev[ge * 3 + 2];
        float rinv = rsqrtf(x * x + y * y + z * z);
        float vx = x * rinv, vy = y * rinv, vz = z * rinv;
        float val;
        if (t < 9) {
            val = (t == 0 || t == 4 || t == 8) ? 1.0f : 0.0f;
        } else if (t < 18) {
            int p = t - 9;
            switch (p) {
                case 1: val = -vz; break;
                case 2: val =  vy; break;
                case 3: val =  vz; break;
                case 5: val = -vx; break;
                case 6: val = -vy; break;
                case 7: val =  vx; break;
                default: val = 0.0f; break;
            }
        } else {
            int p = t - 18;
            int i = p / 3, j = p - 3 * i;
            float ri = (i == 0) ? vx : ((i == 1) ? vy : vz);
            float rj = (j == 0) ? vx : ((j == 1) ? vy : vz);
            val = ri * rj - ((i == j) ? (1.0f / 3.0f) : 0.0f);
        }
        rec[(size_t)ge * 128 + 96 + t] = val;
    }
    __syncthreads();

    // c[m] = (b[m] + rbf.Wd[m]) * env * (F[zi][cc] + G[zj][cc])
    const float* Ft = FG;
    const float* Gt = FG + Z_MAX * C_EMB;
    for (int idx = tid; idx < EPA * 96; idx += TA) {
        int e = idx / 96, m = idx - e * 96, ge = e0 + e;
        int cc = m & 31;
        const float4* Wd  = (const float4*)(dense_W + m * 32);
        const float4* rb4 = (const float4*)s_rbf[e];
        float acc = dense_b[m];
        #pragma unroll
        for (int n = 0; n < 8; ++n) {
            float4 w = Wd[n]; float4 rv = rb4[n];
            acc += w.x * rv.x + w.y * rv.y + w.z * rv.z + w.w * rv.w;
        }
        float hz = Ft[s_zi[e] * 32 + cc] + Gt[s_zj[e] * 32 + cc];
        rec[(size_t)ge * 128 + m] = acc * s_env[e] * hz;
    }
}

// ============ kB: barrier-free pipelined expansion (2 edges / wave) ===========
#define BBLK 1024
#define BT 256
#define NPAIR (N_EDGES / 2)

__global__ __launch_bounds__(BT) void kB_expand(
    const float* __restrict__ rec,   // (N_EDGES, 128)
    float* __restrict__ out)
{
    __shared__ float lds[BT / 64][256];   // 1 KB per wave, wave-private

    const int tid  = threadIdx.x;
    const int lane = tid & 63;
    const int w    = tid >> 6;
    const int gw   = blockIdx.x * (BT / 64) + w;
    const int NW   = BBLK * (BT / 64);

    // per-lane constant index sets: store inst s covers fl4 q of the pair-region
    int el[3], ccc[3][4], ppp[3][4];
    #pragma unroll
    for (int s = 0; s < 3; ++s) {
        int q = s * 64 + lane;           // s=2 only valid for lane<16 (q<144)
        int e_l = q / 72;
        int qq = q - 72 * e_l;
        el[s] = (q < 144) ? e_l : 0;
        #pragma unroll
        for (int u = 0; u < 4; ++u) {
            int f = 4 * qq + u;
            ccc[s][u] = f / 9;
            ppp[s][u] = f - 9 * (f / 9);
        }
    }

    float* sc = lds[w];
    const floatx4* rec4 = (const floatx4*)rec;
    const int half = lane >> 5, sub = lane & 31;

    // prefetch first pair's records (gw < NPAIR always: NW=4096)
    floatx4 g = rec4[(size_t)(2 * gw + half) * 32 + sub];

    for (int p = gw; p < NPAIR; p += NW) {
        // stage current pair into wave LDS
        ((floatx4*)sc)[half * 32 + sub] = g;

        // issue next pair's gather early (hides under store phase)
        int pn = p + NW;
        floatx4 gn = g;
        if (pn < NPAIR) gn = rec4[(size_t)(2 * pn + half) * 32 + sub];

        // 9 contiguous wave-stores (3 regions x 2.25KB)
        #pragma unroll
        for (int r = 0; r < 3; ++r) {
            float* ob = out + (size_t)r * RSZ + (size_t)(2 * p) * 288;
            #pragma unroll
            for (int s = 0; s < 2; ++s) {
                floatx4 v;
                #pragma unroll
                for (int u = 0; u < 4; ++u) {
                    v[u] = sc[el[s] * 128 + 32 * r + ccc[s][u]]
                         * sc[el[s] * 128 + 96 + 9 * r + ppp[s][u]];
                }
                ((floatx4*)ob)[s * 64 + lane] = v;
            }
            if (lane < 16) {
                floatx4 v;
                #pragma unroll
                for (int u = 0; u < 4; ++u) {
                    v[u] = sc[el[2] * 128 + 32 * r + ccc[2][u]]
                         * sc[el[2] * 128 + 96 + 9 * r + ppp[2][u]];
                }
                ((floatx4*)ob)[128 + lane] = v;
            }
        }
        g = gn;
    }
}

// ===================== Fallback: proven R1 single kernel ======================
#define EPBF 16
#define TF 256

__global__ __launch_bounds__(TF) void edge_embed_fallback(
    const int* __restrict__ atomic_numbers,
    const int* __restrict__ nbr,
    const float* __restrict__ ev,
    const float* __restrict__ z_table,
    const float* __restrict__ z_map_W,
    const float* __restrict__ dense_W,
    const float* __restrict__ dense_b,
    const float* __restrict__ rbf_beta,
    const float* __restrict__ rbf_centres,
    float* __restrict__ out)
{
    __shared__ float s_hi[EPBF][C_EMB];
    __shared__ float s_hj[EPBF][C_EMB];
    __shared__ float s_rbf[EPBF][N_RBF];
    __shared__ float s_hz[EPBF][C_EMB];
    __shared__ float s_c[EPBF][96];
    __shared__ float s_basis[EPBF][28];

    const int tid = threadIdx.x;
    const int e0 = blockIdx.x * EPBF;

    for (int idx = tid; idx < EPBF * C_EMB; idx += TF) {
        int e = idx >> 5, k = idx & 31, ge = e0 + e;
        s_hi[e][k] = z_table[atomic_numbers[nbr[ge]] * C_EMB + k];
        s_hj[e][k] = z_table[atomic_numbers[nbr[N_EDGES + ge]] * C_EMB + k];
    }
    for (int idx = tid; idx < EPBF * N_RBF; idx += TF) {
        int e = idx >> 5, n = idx & 31, ge = e0 + e;
        float x = ev[ge * 3 + 0], y = ev[ge * 3 + 1], z = ev[ge * 3 + 2];
        float r = sqrtf(x * x + y * y + z * z);
        float d = __expf(-r) - rbf_centres[n];
        s_rbf[e][n] = __expf(-rbf_beta[n] * d * d);
        if (n == 0)
            s_basis[e][27] = (r < 5.0f) ? 0.5f * (__cosf(PI_F * r * 0.2f) + 1.0f) : 0.0f;
    }
    for (int idx = tid; idx < EPBF * 27; idx += TF) {
        int e = idx / 27, t = idx - e * 27, ge = e0 + e;
        float x = ev[ge * 3 + 0], y = ev[ge * 3 + 1], z = ev[ge * 3 + 2];
        float rinv = rsqrtf(x * x + y * y + z * z);
        float vx = x * rinv, vy = y * rinv, vz = z * rinv;
        float val;
        if (t < 9) val = (t == 0 || t == 4 || t == 8) ? 1.0f : 0.0f;
        else if (t < 18) {
            int p = t - 9;
            switch (p) {
                case 1: val = -vz; break;
                case 2: val =  vy; break;
                case 3: val =  vz; break;
                case 5: val = -vx; break;
                case 6: val = -vy; break;
                case 7: val =  vx; break;
                default: val = 0.0f; break;
            }
        } else {
            int p = t - 18;
            int i = p / 3, j = p - 3 * i;
            float ri = (i == 0) ? vx : ((i == 1) ? vy : vz);
            float rj = (j == 0) ? vx : ((j == 1) ? vy : vz);
            val = ri * rj - ((i == j) ? (1.0f / 3.0f) : 0.0f);
        }
        s_basis[e][t] = val;
    }
    __syncthreads();
    for (int idx = tid; idx < EPBF * C_EMB; idx += TF) {
        int e = idx >> 5, cc = idx & 31;
        const float4* Wi  = (const float4*)(z_map_W + cc * 64);
        const float4* hi4 = (const float4*)s_hi[e];
        const float4* hj4 = (const float4*)s_hj[e];
        float acc = 0.0f;
        #pragma unroll
        for (int k = 0; k < 8; ++k) {
            float4 w = Wi[k]; float4 h = hi4[k];
            acc += w.x * h.x + w.y * h.y + w.z * h.z + w.w * h.w;
        }
        #pragma unroll
        for (int k = 0; k < 8; ++k) {
            float4 w = Wi[8 + k]; float4 h = hj4[k];
            acc += w.x * h.x + w.y * h.y + w.z * h.z + w.w * h.w;
        }
        s_hz[e][cc] = acc;
    }
    __syncthreads();
    for (int idx = tid; idx < EPBF * 96; idx += TF) {
        int e = idx / 96, m = idx - e * 96;
        int cc = m & 31;
        const float4* Wd  = (const float4*)(dense_W + m * 32);
        const float4* rb4 = (const float4*)s_rbf[e];
        float acc = dense_b[m];
        #pragma unroll
        for (int n = 0; n < 8; ++n) {
            float4 w = Wd[n]; float4 rv = rb4[n];
            acc += w.x * rv.x + w.y * rv.y + w.z * rv.z + w.w * rv.w;
        }
        s_c[e][m] = acc * s_basis[e][27] * s_hz[e][cc];
    }
    __syncthreads();
    float* outI = out + (size_t)e0 * 288;
    float* outA = out + RSZ + (size_t)e0 * 288;
    float* outS = out + 2 * RSZ + (size_t)e0 * 288;
    const int NQ = EPBF * 288 / 4;
    for (int q = tid; q < NQ; q += TF) {
        int fbase = q * 4;
        floatx4 aI, aA, aS;
        #pragma unroll
        for (int u = 0; u < 4; ++u) {
            int f = fbase + u;
            int e = f / 288;
            int rem = f - e * 288;
            int cc = rem / 9;
            int p = rem - cc * 9;
            aI[u] = s_c[e][cc]      * s_basis[e][p];
            aA[u] = s_c[e][32 + cc] * s_basis[e][9 + p];
            aS[u] = s_c[e][64 + cc] * s_basis[e][18 + p];
        }
        ((floatx4*)outI)[q] = aI;
        ((floatx4*)outA)[q] = aA;
        ((floatx4*)outS)[q] = aS;
    }
}

extern "C" void kernel_launch(void* const* d_in, const int* in_sizes, int n_in,
                              void* d_out, int out_size, void* d_ws, size_t ws_size,
                              hipStream_t stream) {
    const int*   an  = (const int*)d_in[0];
    const int*   nbr = (const int*)d_in[1];
    const float* ev  = (const float*)d_in[2];
    const float* zt  = (const float*)d_in[3];
    const float* zw  = (const float*)d_in[4];
    const float* dw  = (const float*)d_in[5];
    const float* db  = (const float*)d_in[6];
    const float* rb  = (const float*)d_in[7];
    const float* rc  = (const float*)d_in[8];
    float* outp = (float*)d_out;

    const size_t rec_f = (size_t)N_EDGES * 128;          // 20.48M floats
    const size_t fg_f  = 2 * Z_MAX * C_EMB;              // 7616 floats
    const size_t need  = (rec_f + fg_f) * sizeof(float); // ~82 MB

    if (ws_size >= need) {
        float* rec = (float*)d_ws;
        float* FG  = rec + rec_f;
        k0_tables<<<dim3((2 * Z_MAX * C_EMB + 255) / 256), 256, 0, stream>>>(zt, zw, FG);
        kA_features<<<dim3(N_EDGES / EPA), TA, 0, stream>>>(
            an, nbr, ev, dw, db, rb, rc, FG, rec);
        kB_expand<<<dim3(BBLK), BT, 0, stream>>>(rec, outp);
    } else {
        edge_embed_fallback<<<dim3(N_EDGES / EPBF), TF, 0, stream>>>(
            an, nbr, ev, zt, zw, dw, db, rb, rc, outp);
    }
}